// Round 14
// baseline (209.399 us; speedup 1.0000x reference)
//
#include <hip/hip_runtime.h>
#include <hip/hip_bf16.h>

#define LL 4096
#define DM 96
#define DI 192
#define NS 16
#define RK 6
#define RKP 8              // padded stride for dt coeffs (16B alignment)
#define KD 4
#define CPROJ 38
#define NC (KD*DI*NS)      // 12288 independent chains
#define PT 32              // t-tile for k_proj
#define WS 196             // LDS row stride (4*odd -> quad-bank spread)
#define OT 16              // l-tile for k_oproj
#define L2E 1.44269504f

__device__ __forceinline__ float b2f(__hip_bfloat16 v){ return __bfloat162float(v); }

// inline dtype detect: 64 lanes sample even halfwords of x; bf16 data has sane exponents
__device__ __forceinline__ int detect_bf16(const unsigned short* __restrict__ xh, int tid, int* sflag){
  if (tid < 64){
    unsigned short u = xh[2*tid];
    int e = (u >> 7) & 0xFF;
    int sane = (e >= 107 && e <= 131) ? 1 : 0;
    unsigned long long m = __ballot(sane);
    if (tid == 0) *sflag = (__popcll(m) >= 32) ? 1 : 0;
  }
  return 0;
}

// -------- K0: convert params (inputs 1..11) to fp32 (self-detecting); x handled raw --------
struct P12 { const void* p[12]; };
__global__ void k_convert_all(P12 ptrs, float* __restrict__ dst) {
  // inputs 1..11: ipw, cw, cb, xpw, dtw, dtb, alog, Ds, lng, lnb, opw
  const int off[12] = {0,36864,38592,38784,67968,72576,73344,85632,86400,86592,86784,105216};
  __shared__ int sflag;
  detect_bf16((const unsigned short*)ptrs.p[0], threadIdx.x, &sflag);
  __syncthreads();
  int f = sflag;
  int i = blockIdx.x * 256 + threadIdx.x;
  if (i >= 105216) return;
  int j = 0;
  #pragma unroll
  for (int s = 1; s < 11; s++) if (i >= off[s]) j = s;
  int e = i - off[j];
  const void* src = ptrs.p[j+1];
  if (f) dst[i] = b2f(((const __hip_bfloat16*)src)[e]);
  else   dst[i] = ((const float*)src)[e];
}

// -------- K1: in_proj GEMM; reads raw x (dtype-branch), converted w --------
__global__ void k_inproj(const void* __restrict__ xraw,
                         const float* __restrict__ w,
                         float* __restrict__ xx, float* __restrict__ z) {
  __shared__ float xr[8*DM];
  __shared__ int sflag;
  int tid = threadIdx.x; // 384
  detect_bf16((const unsigned short*)xraw, tid, &sflag);
  __syncthreads();
  int l0 = blockIdx.x * 8;
  if (sflag){
    const __hip_bfloat16* xb = (const __hip_bfloat16*)xraw + (size_t)l0*DM;
    for (int i = tid; i < 8*DM; i += 384) xr[i] = b2f(xb[i]);
  } else {
    const float* xf = (const float*)xraw + (size_t)l0*DM;
    for (int i = tid; i < 8*DM; i += 384) xr[i] = xf[i];
  }
  __syncthreads();
  int e = tid;
  float acc[8];
  #pragma unroll
  for (int i=0;i<8;i++) acc[i]=0.f;
  const float* wr = w + e*DM;
  for (int c=0;c<DM;c++){
    float wv = wr[c];
    #pragma unroll
    for (int i=0;i<8;i++) acc[i] = fmaf(wv, xr[i*DM+c], acc[i]);
  }
  if (e < DI) {
    #pragma unroll
    for (int i=0;i<8;i++) xx[(l0+i)*DI + e] = acc[i];
  } else {
    int e2 = e - DI;
    #pragma unroll
    for (int i=0;i<8;i++) z[(l0+i)*DI + e2] = acc[i];
  }
}

// -------- K2: depthwise 3x3 conv + bias + SiLU; writes xc AND transposed xct --------
__global__ void k_conv(const float* __restrict__ xx,
                       const float* __restrict__ cw,
                       const float* __restrict__ cb,
                       float* __restrict__ xc,
                       float* __restrict__ xct) {
  int l = blockIdx.x;
  int d = threadIdx.x; // 192
  int h = l >> 6, w = l & 63;
  float acc = cb[d];
  #pragma unroll
  for (int ki=0; ki<3; ki++){
    int hh = h + ki - 1;
    if ((unsigned)hh >= 64u) continue;
    #pragma unroll
    for (int kj=0;kj<3;kj++){
      int wj = w + kj - 1;
      if ((unsigned)wj >= 64u) continue;
      acc = fmaf(cw[d*9 + ki*3 + kj], xx[(hh*64+wj)*DI + d], acc);
    }
  }
  float v = acc / (1.f + __expf(-acc));
  xc[l*DI + d] = v;
  xct[(((w<<6)|h))*DI + d] = v;
}

__device__ __forceinline__ int dir_map(int k, int t){
  if (k==0) return t;
  if (k==1) return ((t&63)<<6) | (t>>6);
  if (k==2) return 4095 - t;
  int u = 4095 - t; return ((u&63)<<6) | (u>>6);
}

// -------- K3: x_dbl projection as register-tiled LDS GEMM --------
__global__ void __launch_bounds__(256) k_proj(const float* __restrict__ xc,
                       const float* __restrict__ xpw,
                       float* __restrict__ dts,
                       float* __restrict__ Bb, float* __restrict__ Cb) {
  __shared__ float wl[CPROJ*WS];   // 29.8 KB
  __shared__ float xs[PT*WS];      // 25.1 KB
  int b = blockIdx.x;              // KD * 128
  int k = b >> 7;
  int t_base = (b & 127) * PT;
  int tid = threadIdx.x;
  for (int idx = tid; idx < CPROJ*DI; idx += 256){
    int cc = idx / DI, j = idx - cc*DI;
    wl[cc*WS + j] = xpw[(k*CPROJ + cc)*DI + j];
  }
  for (int idx = tid; idx < PT*DI; idx += 256){
    int tt = idx / DI, j = idx - tt*DI;
    xs[tt*WS + j] = xc[dir_map(k, t_base + tt)*DI + j];
  }
  __syncthreads();
  int tg = tid & 7;        // t-group: cols {tg, tg+8, tg+16, tg+24}
  int ty = tid >> 3;       // 0..31: rows {ty, ty+32 if <38}
  int cc0 = ty;
  int has2 = (ty + 32 < CPROJ);
  int cc1 = has2 ? (ty + 32) : ty;
  float a0x=0.f,a0y=0.f,a0z=0.f,a0w=0.f;
  float a1x=0.f,a1y=0.f,a1z=0.f,a1w=0.f;
  const float4* w0p = (const float4*)&wl[cc0*WS];
  const float4* w1p = (const float4*)&wl[cc1*WS];
  const float4* x0p = (const float4*)&xs[(tg     )*WS];
  const float4* x1p = (const float4*)&xs[(tg +  8)*WS];
  const float4* x2p = (const float4*)&xs[(tg + 16)*WS];
  const float4* x3p = (const float4*)&xs[(tg + 24)*WS];
  #pragma unroll 4
  for (int jc = 0; jc < DI/4; jc++){
    float4 w0 = w0p[jc], w1 = w1p[jc];
    float4 x0 = x0p[jc], x1 = x1p[jc], x2 = x2p[jc], x3 = x3p[jc];
    a0x = fmaf(w0.x,x0.x,fmaf(w0.y,x0.y,fmaf(w0.z,x0.z,fmaf(w0.w,x0.w,a0x))));
    a0y = fmaf(w0.x,x1.x,fmaf(w0.y,x1.y,fmaf(w0.z,x1.z,fmaf(w0.w,x1.w,a0y))));
    a0z = fmaf(w0.x,x2.x,fmaf(w0.y,x2.y,fmaf(w0.z,x2.z,fmaf(w0.w,x2.w,a0z))));
    a0w = fmaf(w0.x,x3.x,fmaf(w0.y,x3.y,fmaf(w0.z,x3.z,fmaf(w0.w,x3.w,a0w))));
    a1x = fmaf(w1.x,x0.x,fmaf(w1.y,x0.y,fmaf(w1.z,x0.z,fmaf(w1.w,x0.w,a1x))));
    a1y = fmaf(w1.x,x1.x,fmaf(w1.y,x1.y,fmaf(w1.z,x1.z,fmaf(w1.w,x1.w,a1y))));
    a1z = fmaf(w1.x,x2.x,fmaf(w1.y,x2.y,fmaf(w1.z,x2.z,fmaf(w1.w,x2.w,a1z))));
    a1w = fmaf(w1.x,x3.x,fmaf(w1.y,x3.y,fmaf(w1.z,x3.z,fmaf(w1.w,x3.w,a1w))));
  }
  float accs0[4] = {a0x,a0y,a0z,a0w};
  float accs1[4] = {a1x,a1y,a1z,a1w};
  #pragma unroll
  for (int i=0;i<4;i++){
    int t = t_base + tg + 8*i;
    size_t kt = (size_t)k*LL + t;
    {
      int cc = cc0; float v = accs0[i];
      if (cc < RK)            dts[kt*RKP + cc] = v;
      else if (cc < RK+NS)    Bb [kt*NS + (cc-RK)] = v;
      else                    Cb [kt*NS + (cc-RK-NS)] = v;
    }
    if (has2){
      int cc = ty + 32; float v = accs1[i];
      if (cc < RK+NS)         Bb [kt*NS + (cc-RK)] = v;
      else                    Cb [kt*NS + (cc-RK-NS)] = v;
    }
  }
}

// -------- K4a: single scan pass; plain stores into ydir[k][t][d] (t-space) --------
template<int CHB>
__global__ void __launch_bounds__(256) k_scan1(
                      const float* __restrict__ xc_hw,
                      const float* __restrict__ xc_wh,
                      const float* __restrict__ dts,
                      const float* __restrict__ Bbuf,
                      const float* __restrict__ Cbuf,
                      const float* __restrict__ A_logs,
                      const float* __restrict__ dtw,
                      const float* __restrict__ dtb,
                      float* __restrict__ Pb, float* __restrict__ Hb,
                      float* __restrict__ SDb,
                      float* __restrict__ ydir) {
  constexpr int CS = LL >> CHB;
  int b = blockIdx.x;             // ((k*3+dg3)<<CHB) | c
  int c = b & ((1<<CHB)-1);
  int kg = b >> CHB;
  int k = kg / 3, dg3 = kg - k*3;
  int tid = threadIdx.x;
  int dl = tid >> 2, nq = tid & 3;
  int d = dg3*64 + dl;
  int kd = k*DI + d;
  float4 Al = *(const float4*)&A_logs[kd*NS + nq*4];
  float A0 = -__expf(Al.x)*L2E, A1 = -__expf(Al.y)*L2E;
  float A2 = -__expf(Al.z)*L2E, A3 = -__expf(Al.w)*L2E;
  float bt = dtb[kd];
  float w0 = dtw[kd*RK+0], w1 = dtw[kd*RK+1], w2 = dtw[kd*RK+2];
  float w3 = dtw[kd*RK+3], w4 = dtw[kd*RK+4], w5 = dtw[kd*RK+5];
  const float* dr = dts + ((size_t)k*LL + c*CS)*RKP;
  const float4* bp = (const float4*)(Bbuf + ((size_t)k*LL + c*CS)*NS) + nq;
  const float4* cp = (const float4*)(Cbuf + ((size_t)k*LL + c*CS)*NS) + nq;
  const float* xbase = (k & 1) ? xc_wh : xc_hw;
  int l0 = (k < 2) ? (c*CS) : (4095 - c*CS);
  int lstep = (k < 2) ? DI : -DI;
  const float* xp = xbase + (size_t)l0*DI + d;
  float* yp = ydir + ((size_t)k*LL + c*CS)*DI + d;
  float* sdp = SDb + ((size_t)k*LL + c*CS)*DI + d;
  float h0=0.f,h1=0.f,h2=0.f,h3=0.f, cumD=0.f;
  #pragma unroll
  for (int s=0; s<CS; s++){
    float4 lo = *(const float4*)(dr + s*RKP);
    float4 hi = *(const float4*)(dr + s*RKP + 4);
    float v = bt;
    v = fmaf(w0, lo.x, v); v = fmaf(w1, lo.y, v); v = fmaf(w2, lo.z, v);
    v = fmaf(w3, lo.w, v); v = fmaf(w4, hi.x, v); v = fmaf(w5, hi.y, v);
    float sp = (v > 20.f) ? v : __logf(1.f + __expf(v));
    cumD += sp;
    float sx = sp * xp[(ptrdiff_t)s*lstep];
    float4 bv = bp[s*4];
    float4 cv = cp[s*4];
    float a;
    a = exp2f(sp*A0); h0 = fmaf(a, h0, sx*bv.x);
    a = exp2f(sp*A1); h1 = fmaf(a, h1, sx*bv.y);
    a = exp2f(sp*A2); h2 = fmaf(a, h2, sx*bv.z);
    a = exp2f(sp*A3); h3 = fmaf(a, h3, sx*bv.w);
    float y = h0*cv.x + h1*cv.y + h2*cv.z + h3*cv.w;
    y += __shfl_xor(y, 1, 64);
    y += __shfl_xor(y, 2, 64);
    if (nq == 0){
      yp[s*DI] = y;          // plain store: unique writer per (k,t,d)
      sdp[s*DI] = cumD;
    }
  }
  int base = c*NC + kd*NS + nq*4;
  *(float4*)&Pb[base] = make_float4(exp2f(A0*cumD), exp2f(A1*cumD),
                                    exp2f(A2*cumD), exp2f(A3*cumD));
  *(float4*)&Hb[base] = make_float4(h0,h1,h2,h3);
}

// -------- K4b: phase-2 combine, IN-PLACE: Hb[c] <- chunk-entry state --------
template<int CHB>
__global__ void __launch_bounds__(256) k_scan2(
                      const float* __restrict__ Pb, float* __restrict__ Hb) {
  constexpr int CH = 1 << CHB;
  int idx = blockIdx.x*256 + threadIdx.x;   // < 12288
  float h = 0.f;
  #pragma unroll 8
  for (int c=0;c<CH;c++){
    float P = Pb[c*NC + idx];
    float Hc = Hb[c*NC + idx];
    Hb[c*NC + idx] = h;
    h = fmaf(P, h, Hc);
  }
}

// -------- K4c: parallel correction (non-atomic RMW of own chunk) --------
template<int CHB>
__global__ void __launch_bounds__(192) k_corr(
                      const float* __restrict__ Cbuf,
                      const float* __restrict__ A_logs,
                      const float* __restrict__ Hb,     // entry states
                      const float* __restrict__ SDb,
                      float* __restrict__ ydir) {
  constexpr int CS = LL >> CHB;
  int b = blockIdx.x;              // KD << CHB
  int k = b >> CHB;
  int c = b & ((1<<CHB)-1);
  if (c == 0) return;              // entry state is zero -> no correction
  int t0 = c*CS;
  int d = threadIdx.x;             // 192
  int kd = k*DI + d;
  __shared__ float cs[CS*NS];
  for (int i = d; i < CS*NS; i += 192)
    cs[i] = Cbuf[((size_t)k*LL + t0)*NS + i];
  float A2[16], he[16];
  {
    const float4* ap = (const float4*)&A_logs[kd*NS];
    const float4* hp = (const float4*)&Hb[c*NC + kd*NS];
    #pragma unroll
    for (int i=0;i<4;i++){
      float4 av = ap[i];
      A2[4*i+0] = -__expf(av.x)*L2E; A2[4*i+1] = -__expf(av.y)*L2E;
      A2[4*i+2] = -__expf(av.z)*L2E; A2[4*i+3] = -__expf(av.w)*L2E;
      *(float4*)&he[4*i] = hp[i];
    }
  }
  __syncthreads();
  float* yp = ydir + ((size_t)k*LL + t0)*DI + d;
  const float* sdp = SDb + ((size_t)k*LL + t0)*DI + d;
  #pragma unroll 4
  for (int s=0; s<CS; s++){
    float SD = sdp[s*DI];
    float corr = 0.f;
    #pragma unroll
    for (int n=0;n<16;n++)
      corr = fmaf(cs[s*NS+n]*exp2f(A2[n]*SD), he[n], corr);
    yp[s*DI] += corr;        // unique owner: scan1 done, one block per chunk
  }
}

// -------- K5a: gather 4 dirs + x*sumD, LayerNorm, *silu(z) -> g --------
__global__ void k_ln(const float* __restrict__ ydir,
                     const float* __restrict__ xc,
                     const float* __restrict__ z,
                     const float* __restrict__ Ds,
                     const float* __restrict__ ln_g,
                     const float* __restrict__ ln_b,
                     float* __restrict__ g) {
  int l = blockIdx.x;
  int d = threadIdx.x; // 192
  int lt = ((l & 63) << 6) | (l >> 6);
  float y = ydir[(size_t)l*DI + d]
          + ydir[((size_t)LL   + lt)*DI + d]
          + ydir[((size_t)2*LL + (4095 - l))*DI + d]
          + ydir[((size_t)3*LL + (4095 - lt))*DI + d];
  float dsum = Ds[0*DI+d] + Ds[1*DI+d] + Ds[2*DI+d] + Ds[3*DI+d];
  y = fmaf(xc[l*DI+d], dsum, y);
  float s1 = y, s2 = y*y;
  #pragma unroll
  for (int off=32; off; off>>=1){
    s1 += __shfl_xor(s1, off, 64);
    s2 += __shfl_xor(s2, off, 64);
  }
  __shared__ float red[6];
  int wave = d >> 6;
  if ((d & 63) == 0){ red[wave] = s1; red[3+wave] = s2; }
  __syncthreads();
  float sum = red[0]+red[1]+red[2];
  float sq  = red[3]+red[4]+red[5];
  float mu = sum * (1.f/192.f);
  float var = sq * (1.f/192.f) - mu*mu;
  float rstd = rsqrtf(var + 1e-5f);
  float yn = (y - mu) * rstd * ln_g[d] + ln_b[d];
  float zv = z[l*DI + d];
  g[(size_t)l*DI + d] = yn * (zv / (1.f + __expf(-zv)));
}

// -------- K5b: out_proj GEMM (4096x192)*(192x96)^T, 16-l tile, 8 acc/thread --------
__global__ void __launch_bounds__(192) k_oproj(const float* __restrict__ g,
                      const float* __restrict__ opw,
                      void* __restrict__ out,
                      const unsigned short* __restrict__ xh) {
  __shared__ float gs[OT*WS];      // 12.5 KB
  __shared__ int sflag;
  int tid = threadIdx.x;           // 192
  detect_bf16(xh, tid, &sflag);
  int l0 = blockIdx.x * OT;        // 256 blocks
  const float4* gsrc = (const float4*)(g + (size_t)l0*DI);
  for (int idx = tid; idx < OT*DI/4; idx += 192){
    int row = idx / 48, col = idx - row*48;
    float4 v = gsrc[idx];
    *(float4*)&gs[row*WS + col*4] = v;
  }
  __syncthreads();
  int half = tid / 96;             // 0/1 -> rows half*8..half*8+7
  int e = tid - half*96;
  int r0 = half*8;
  float acc[8];
  #pragma unroll
  for (int i=0;i<8;i++) acc[i] = 0.f;
  const float4* wrow = (const float4*)(opw + e*DI);
  #pragma unroll 4
  for (int jc = 0; jc < DI/4; jc++){
    float4 w = wrow[jc];
    #pragma unroll
    for (int i=0;i<8;i++){
      float4 gv = *(const float4*)&gs[(r0+i)*WS + jc*4];
      acc[i] = fmaf(w.x,gv.x,fmaf(w.y,gv.y,fmaf(w.z,gv.z,fmaf(w.w,gv.w,acc[i]))));
    }
  }
  int f = sflag;
  #pragma unroll
  for (int i=0;i<8;i++){
    int l = l0 + r0 + i;
    if (f) ((__hip_bfloat16*)out)[l*DM + e] = __float2bfloat16(acc[i]);
    else   ((float*)out)[l*DM + e] = acc[i];
  }
}

extern "C" void kernel_launch(void* const* d_in, const int* in_sizes, int n_in,
                              void* d_out, int out_size, void* d_ws, size_t ws_size,
                              hipStream_t stream) {
  float* ws = (float*)d_ws;
  float* cvt = ws + 16;
  // converted params (inputs 1..11)
  const int off[12] = {0,36864,38592,38784,67968,72576,73344,85632,86400,86592,86784,105216};
  float* c[12];
  c[0] = nullptr;                            // x stays raw
  for (int i = 1; i < 12; i++) c[i] = cvt + off[i-1];

  float* big    = cvt + 105216;
  float* xx     = big;                       // 786432
  float* z      = xx + (size_t)LL*DI;        // 786432
  float* xc     = z  + (size_t)LL*DI;        // 786432
  float* xct    = xc + (size_t)LL*DI;        // 786432
  float* dts    = xct + (size_t)LL*DI;       // 131072 (RKP=8 padded)
  float* Bb     = dts + (size_t)KD*LL*RKP;   // 262144
  float* Cb     = Bb + (size_t)KD*LL*NS;     // 262144
  float* Pb     = Cb + (size_t)KD*LL*NS;     // CHn*NC
  // footprint(CHB=8): ~66 MB; (CHB=6): ~43 MB. ws_size measured 256 MiB.
  size_t need256 = (size_t)(16 + 105216 + 4*786432 + 131072 + 2*262144
                            + 2*256*NC + 2*(size_t)KD*LL*DI) * 4;
  int chBits = (ws_size >= need256) ? 8 : 6;
  int CHn = 1 << chBits;
  float* Hb   = Pb + (size_t)CHn*NC;
  float* SDb  = Hb + (size_t)CHn*NC;         // KD*LL*DI = 3145728
  float* ydir = SDb + (size_t)KD*LL*DI;      // KD*LL*DI = 3145728
  float* g    = Pb;                          // alias: Pb dead after scan2

  P12 ptrs;
  for (int i = 0; i < 12; i++) ptrs.p[i] = d_in[i];
  k_convert_all<<<(105216 + 255)/256, 256, 0, stream>>>(ptrs, cvt);

  k_inproj<<<LL/8, 384, 0, stream>>>(d_in[0], c[1], xx, z);
  k_conv<<<LL, DI, 0, stream>>>(xx, c[2], c[3], xc, xct);
  k_proj<<<KD*(LL/PT), 256, 0, stream>>>(xc, c[4], dts, Bb, Cb);
  if (chBits == 8){
    k_scan1<8><<<KD*3*256, 256, 0, stream>>>(xc, xct, dts, Bb, Cb, c[7], c[5], c[6],
                                             Pb, Hb, SDb, ydir);
    k_scan2<8><<<NC/256, 256, 0, stream>>>(Pb, Hb);
    k_corr<8><<<KD*256, 192, 0, stream>>>(Cb, c[7], Hb, SDb, ydir);
  } else {
    k_scan1<6><<<KD*3*64, 256, 0, stream>>>(xc, xct, dts, Bb, Cb, c[7], c[5], c[6],
                                            Pb, Hb, SDb, ydir);
    k_scan2<6><<<NC/256, 256, 0, stream>>>(Pb, Hb);
    k_corr<6><<<KD*64, 192, 0, stream>>>(Cb, c[7], Hb, SDb, ydir);
  }
  k_ln<<<LL, DI, 0, stream>>>(ydir, xc, z, c[8], c[9], c[10], g);
  k_oproj<<<LL/OT, 192, 0, stream>>>(g, c[11], d_out, (const unsigned short*)d_in[0]);
}

// Round 15
// 202.750 us; speedup vs baseline: 1.0328x; 1.0328x over previous
//
#include <hip/hip_runtime.h>
#include <hip/hip_bf16.h>

#define LL 4096
#define DM 96
#define DI 192
#define NS 16
#define RK 6
#define RKP 8              // padded stride for dt coeffs (16B alignment)
#define KD 4
#define CPROJ 38
#define NC (KD*DI*NS)      // 12288 independent chains
#define PT 32              // t-tile for k_proj
#define WS 196             // LDS row stride (4*odd -> quad-bank spread)
#define OT 16              // l-tile for k_out
#define L2E 1.44269504f

__device__ __forceinline__ float b2f(__hip_bfloat16 v){ return __bfloat162float(v); }

// inline dtype detect: 64 lanes sample even halfwords of x; bf16 data has sane exponents
__device__ __forceinline__ int detect_bf16(const unsigned short* __restrict__ xh, int tid, int* sflag){
  if (tid < 64){
    unsigned short u = xh[2*tid];
    int e = (u >> 7) & 0xFF;
    int sane = (e >= 107 && e <= 131) ? 1 : 0;
    unsigned long long m = __ballot(sane);
    if (tid == 0) *sflag = (__popcll(m) >= 32) ? 1 : 0;
  }
  return 0;
}

// -------- K0: convert params (inputs 1..11) to fp32 (self-detecting); x handled raw --------
struct P12 { const void* p[12]; };
__global__ void k_convert_all(P12 ptrs, float* __restrict__ dst) {
  const int off[12] = {0,36864,38592,38784,67968,72576,73344,85632,86400,86592,86784,105216};
  __shared__ int sflag;
  detect_bf16((const unsigned short*)ptrs.p[0], threadIdx.x, &sflag);
  __syncthreads();
  int f = sflag;
  int i = blockIdx.x * 256 + threadIdx.x;
  if (i >= 105216) return;
  int j = 0;
  #pragma unroll
  for (int s = 1; s < 11; s++) if (i >= off[s]) j = s;
  int e = i - off[j];
  const void* src = ptrs.p[j+1];
  if (f) dst[i] = b2f(((const __hip_bfloat16*)src)[e]);
  else   dst[i] = ((const float*)src)[e];
}

// -------- K1: in_proj GEMM; reads raw x (dtype-branch), converted w --------
__global__ void k_inproj(const void* __restrict__ xraw,
                         const float* __restrict__ w,
                         float* __restrict__ xx, float* __restrict__ z) {
  __shared__ float xr[8*DM];
  __shared__ int sflag;
  int tid = threadIdx.x; // 384
  detect_bf16((const unsigned short*)xraw, tid, &sflag);
  __syncthreads();
  int l0 = blockIdx.x * 8;
  if (sflag){
    const __hip_bfloat16* xb = (const __hip_bfloat16*)xraw + (size_t)l0*DM;
    for (int i = tid; i < 8*DM; i += 384) xr[i] = b2f(xb[i]);
  } else {
    const float* xf = (const float*)xraw + (size_t)l0*DM;
    for (int i = tid; i < 8*DM; i += 384) xr[i] = xf[i];
  }
  __syncthreads();
  int e = tid;
  float acc[8];
  #pragma unroll
  for (int i=0;i<8;i++) acc[i]=0.f;
  const float* wr = w + e*DM;
  for (int c=0;c<DM;c++){
    float wv = wr[c];
    #pragma unroll
    for (int i=0;i<8;i++) acc[i] = fmaf(wv, xr[i*DM+c], acc[i]);
  }
  if (e < DI) {
    #pragma unroll
    for (int i=0;i<8;i++) xx[(l0+i)*DI + e] = acc[i];
  } else {
    int e2 = e - DI;
    #pragma unroll
    for (int i=0;i<8;i++) z[(l0+i)*DI + e2] = acc[i];
  }
}

// -------- K2: depthwise 3x3 conv + bias + SiLU; writes xc AND transposed xct --------
__global__ void k_conv(const float* __restrict__ xx,
                       const float* __restrict__ cw,
                       const float* __restrict__ cb,
                       float* __restrict__ xc,
                       float* __restrict__ xct) {
  int l = blockIdx.x;
  int d = threadIdx.x; // 192
  int h = l >> 6, w = l & 63;
  float acc = cb[d];
  #pragma unroll
  for (int ki=0; ki<3; ki++){
    int hh = h + ki - 1;
    if ((unsigned)hh >= 64u) continue;
    #pragma unroll
    for (int kj=0;kj<3;kj++){
      int wj = w + kj - 1;
      if ((unsigned)wj >= 64u) continue;
      acc = fmaf(cw[d*9 + ki*3 + kj], xx[(hh*64+wj)*DI + d], acc);
    }
  }
  float v = acc / (1.f + __expf(-acc));
  xc[l*DI + d] = v;
  xct[(((w<<6)|h))*DI + d] = v;
}

__device__ __forceinline__ int dir_map(int k, int t){
  if (k==0) return t;
  if (k==1) return ((t&63)<<6) | (t>>6);
  if (k==2) return 4095 - t;
  int u = 4095 - t; return ((u&63)<<6) | (u>>6);
}

// -------- K3: x_dbl projection as register-tiled LDS GEMM --------
__global__ void __launch_bounds__(256) k_proj(const float* __restrict__ xc,
                       const float* __restrict__ xpw,
                       float* __restrict__ dts,
                       float* __restrict__ Bb, float* __restrict__ Cb) {
  __shared__ float wl[CPROJ*WS];   // 29.8 KB
  __shared__ float xs[PT*WS];      // 25.1 KB
  int b = blockIdx.x;              // KD * 128
  int k = b >> 7;
  int t_base = (b & 127) * PT;
  int tid = threadIdx.x;
  for (int idx = tid; idx < CPROJ*DI; idx += 256){
    int cc = idx / DI, j = idx - cc*DI;
    wl[cc*WS + j] = xpw[(k*CPROJ + cc)*DI + j];
  }
  for (int idx = tid; idx < PT*DI; idx += 256){
    int tt = idx / DI, j = idx - tt*DI;
    xs[tt*WS + j] = xc[dir_map(k, t_base + tt)*DI + j];
  }
  __syncthreads();
  int tg = tid & 7;        // t-group: cols {tg, tg+8, tg+16, tg+24}
  int ty = tid >> 3;       // 0..31: rows {ty, ty+32 if <38}
  int cc0 = ty;
  int has2 = (ty + 32 < CPROJ);
  int cc1 = has2 ? (ty + 32) : ty;
  float a0x=0.f,a0y=0.f,a0z=0.f,a0w=0.f;
  float a1x=0.f,a1y=0.f,a1z=0.f,a1w=0.f;
  const float4* w0p = (const float4*)&wl[cc0*WS];
  const float4* w1p = (const float4*)&wl[cc1*WS];
  const float4* x0p = (const float4*)&xs[(tg     )*WS];
  const float4* x1p = (const float4*)&xs[(tg +  8)*WS];
  const float4* x2p = (const float4*)&xs[(tg + 16)*WS];
  const float4* x3p = (const float4*)&xs[(tg + 24)*WS];
  #pragma unroll 4
  for (int jc = 0; jc < DI/4; jc++){
    float4 w0 = w0p[jc], w1 = w1p[jc];
    float4 x0 = x0p[jc], x1 = x1p[jc], x2 = x2p[jc], x3 = x3p[jc];
    a0x = fmaf(w0.x,x0.x,fmaf(w0.y,x0.y,fmaf(w0.z,x0.z,fmaf(w0.w,x0.w,a0x))));
    a0y = fmaf(w0.x,x1.x,fmaf(w0.y,x1.y,fmaf(w0.z,x1.z,fmaf(w0.w,x1.w,a0y))));
    a0z = fmaf(w0.x,x2.x,fmaf(w0.y,x2.y,fmaf(w0.z,x2.z,fmaf(w0.w,x2.w,a0z))));
    a0w = fmaf(w0.x,x3.x,fmaf(w0.y,x3.y,fmaf(w0.z,x3.z,fmaf(w0.w,x3.w,a0w))));
    a1x = fmaf(w1.x,x0.x,fmaf(w1.y,x0.y,fmaf(w1.z,x0.z,fmaf(w1.w,x0.w,a1x))));
    a1y = fmaf(w1.x,x1.x,fmaf(w1.y,x1.y,fmaf(w1.z,x1.z,fmaf(w1.w,x1.w,a1y))));
    a1z = fmaf(w1.x,x2.x,fmaf(w1.y,x2.y,fmaf(w1.z,x2.z,fmaf(w1.w,x2.w,a1z))));
    a1w = fmaf(w1.x,x3.x,fmaf(w1.y,x3.y,fmaf(w1.z,x3.z,fmaf(w1.w,x3.w,a1w))));
  }
  float accs0[4] = {a0x,a0y,a0z,a0w};
  float accs1[4] = {a1x,a1y,a1z,a1w};
  #pragma unroll
  for (int i=0;i<4;i++){
    int t = t_base + tg + 8*i;
    size_t kt = (size_t)k*LL + t;
    {
      int cc = cc0; float v = accs0[i];
      if (cc < RK)            dts[kt*RKP + cc] = v;
      else if (cc < RK+NS)    Bb [kt*NS + (cc-RK)] = v;
      else                    Cb [kt*NS + (cc-RK-NS)] = v;
    }
    if (has2){
      int cc = ty + 32; float v = accs1[i];
      if (cc < RK+NS)         Bb [kt*NS + (cc-RK)] = v;
      else                    Cb [kt*NS + (cc-RK-NS)] = v;
    }
  }
}

// -------- K4a: single scan pass; plain stores into ydir/SDb; PH interleaved (P,H) --------
template<int CHB>
__global__ void __launch_bounds__(256) k_scan1(
                      const float* __restrict__ xc_hw,
                      const float* __restrict__ xc_wh,
                      const float* __restrict__ dts,
                      const float* __restrict__ Bbuf,
                      const float* __restrict__ Cbuf,
                      const float* __restrict__ A_logs,
                      const float* __restrict__ dtw,
                      const float* __restrict__ dtb,
                      float* __restrict__ PH,
                      float* __restrict__ SDb,
                      float* __restrict__ ydir) {
  constexpr int CS = LL >> CHB;
  int b = blockIdx.x;             // ((k*3+dg3)<<CHB) | c
  int c = b & ((1<<CHB)-1);
  int kg = b >> CHB;
  int k = kg / 3, dg3 = kg - k*3;
  int tid = threadIdx.x;
  int dl = tid >> 2, nq = tid & 3;
  int d = dg3*64 + dl;
  int kd = k*DI + d;
  float4 Al = *(const float4*)&A_logs[kd*NS + nq*4];
  float A0 = -__expf(Al.x)*L2E, A1 = -__expf(Al.y)*L2E;
  float A2 = -__expf(Al.z)*L2E, A3 = -__expf(Al.w)*L2E;
  float bt = dtb[kd];
  float w0 = dtw[kd*RK+0], w1 = dtw[kd*RK+1], w2 = dtw[kd*RK+2];
  float w3 = dtw[kd*RK+3], w4 = dtw[kd*RK+4], w5 = dtw[kd*RK+5];
  const float* dr = dts + ((size_t)k*LL + c*CS)*RKP;
  const float4* bp = (const float4*)(Bbuf + ((size_t)k*LL + c*CS)*NS) + nq;
  const float4* cp = (const float4*)(Cbuf + ((size_t)k*LL + c*CS)*NS) + nq;
  const float* xbase = (k & 1) ? xc_wh : xc_hw;
  int l0 = (k < 2) ? (c*CS) : (4095 - c*CS);
  int lstep = (k < 2) ? DI : -DI;
  const float* xp = xbase + (size_t)l0*DI + d;
  float* yp = ydir + ((size_t)k*LL + c*CS)*DI + d;
  float* sdp = SDb + ((size_t)k*LL + c*CS)*DI + d;
  float h0=0.f,h1=0.f,h2=0.f,h3=0.f, cumD=0.f;
  #pragma unroll
  for (int s=0; s<CS; s++){
    float4 lo = *(const float4*)(dr + s*RKP);
    float4 hi = *(const float4*)(dr + s*RKP + 4);
    float v = bt;
    v = fmaf(w0, lo.x, v); v = fmaf(w1, lo.y, v); v = fmaf(w2, lo.z, v);
    v = fmaf(w3, lo.w, v); v = fmaf(w4, hi.x, v); v = fmaf(w5, hi.y, v);
    float sp = (v > 20.f) ? v : __logf(1.f + __expf(v));
    cumD += sp;
    float sx = sp * xp[(ptrdiff_t)s*lstep];
    float4 bv = bp[s*4];
    float4 cv = cp[s*4];
    float a;
    a = exp2f(sp*A0); h0 = fmaf(a, h0, sx*bv.x);
    a = exp2f(sp*A1); h1 = fmaf(a, h1, sx*bv.y);
    a = exp2f(sp*A2); h2 = fmaf(a, h2, sx*bv.z);
    a = exp2f(sp*A3); h3 = fmaf(a, h3, sx*bv.w);
    float y = h0*cv.x + h1*cv.y + h2*cv.z + h3*cv.w;
    y += __shfl_xor(y, 1, 64);
    y += __shfl_xor(y, 2, 64);
    if (nq == 0){
      yp[s*DI] = y;          // plain store: unique writer per (k,t,d)
      sdp[s*DI] = cumD;
    }
  }
  size_t base2 = ((size_t)c*NC + kd*NS + nq*4)*2;
  *(float4*)&PH[base2]   = make_float4(exp2f(A0*cumD), h0, exp2f(A1*cumD), h1);
  *(float4*)&PH[base2+4] = make_float4(exp2f(A2*cumD), h2, exp2f(A3*cumD), h3);
}

// -------- K4b: phase-2 combine over interleaved PH; entry state written into .y --------
template<int CHB>
__global__ void __launch_bounds__(256) k_scan2(float2* __restrict__ PH) {
  constexpr int CH = 1 << CHB;
  int idx = blockIdx.x*256 + threadIdx.x;   // < 12288
  float h = 0.f;
  #pragma unroll 8
  for (int c=0;c<CH;c++){
    float2 ph = PH[(size_t)c*NC + idx];
    PH[(size_t)c*NC + idx].y = h;           // overwrite H with entry state
    h = fmaf(ph.x, h, ph.y);
  }
}

// -------- K4c: parallel correction (non-atomic RMW of own chunk) --------
template<int CHB>
__global__ void __launch_bounds__(192) k_corr(
                      const float* __restrict__ Cbuf,
                      const float* __restrict__ A_logs,
                      const float2* __restrict__ PH,    // .y = entry states
                      const float* __restrict__ SDb,
                      float* __restrict__ ydir) {
  constexpr int CS = LL >> CHB;
  int b = blockIdx.x;              // KD << CHB
  int k = b >> CHB;
  int c = b & ((1<<CHB)-1);
  if (c == 0) return;              // entry state is zero -> no correction
  int t0 = c*CS;
  int d = threadIdx.x;             // 192
  int kd = k*DI + d;
  __shared__ float cs[CS*NS];
  for (int i = d; i < CS*NS; i += 192)
    cs[i] = Cbuf[((size_t)k*LL + t0)*NS + i];
  float A2[16], he[16];
  {
    const float4* ap = (const float4*)&A_logs[kd*NS];
    const float2* hp = PH + (size_t)c*NC + kd*NS;
    #pragma unroll
    for (int i=0;i<4;i++){
      float4 av = ap[i];
      A2[4*i+0] = -__expf(av.x)*L2E; A2[4*i+1] = -__expf(av.y)*L2E;
      A2[4*i+2] = -__expf(av.z)*L2E; A2[4*i+3] = -__expf(av.w)*L2E;
    }
    #pragma unroll
    for (int n=0;n<16;n++) he[n] = hp[n].y;
  }
  __syncthreads();
  float* yp = ydir + ((size_t)k*LL + t0)*DI + d;
  const float* sdp = SDb + ((size_t)k*LL + t0)*DI + d;
  #pragma unroll 4
  for (int s=0; s<CS; s++){
    float SD = sdp[s*DI];
    float corr = 0.f;
    #pragma unroll
    for (int n=0;n<16;n++)
      corr = fmaf(cs[s*NS+n]*exp2f(A2[n]*SD), he[n], corr);
    yp[s*DI] += corr;        // unique owner: scan1 done, one block per chunk
  }
}

// -------- K5: fused gather + LayerNorm + gate + out_proj, 16-l tile --------
__global__ void __launch_bounds__(192) k_out(
                      const float* __restrict__ ydir,
                      const float* __restrict__ xc,
                      const float* __restrict__ z,
                      const float* __restrict__ Ds,
                      const float* __restrict__ ln_g,
                      const float* __restrict__ ln_b,
                      const float* __restrict__ opw,
                      void* __restrict__ out,
                      const unsigned short* __restrict__ xh) {
  __shared__ float gs[OT*WS];      // 12.5 KB: y -> g
  __shared__ float ps[2][OT][12];
  __shared__ float mv[2][OT];
  __shared__ int sflag;
  int tid = threadIdx.x;           // 192
  int d = tid;
  detect_bf16(xh, tid, &sflag);
  int l0 = blockIdx.x * OT;        // 256 blocks
  float dsum = Ds[d] + Ds[DI+d] + Ds[2*DI+d] + Ds[3*DI+d];
  // phase A: y for 16 rows at this d
  #pragma unroll 4
  for (int r=0;r<OT;r++){
    int l = l0 + r;
    int lt = ((l & 63) << 6) | (l >> 6);
    float y = ydir[(size_t)l*DI + d]
            + ydir[((size_t)LL   + lt)*DI + d]
            + ydir[((size_t)2*LL + (4095 - l))*DI + d]
            + ydir[((size_t)3*LL + (4095 - lt))*DI + d];
    gs[r*WS + d] = fmaf(xc[(size_t)l*DI + d], dsum, y);
  }
  __syncthreads();
  // phase B: per-row mean/var; 16 groups x 12 threads
  {
    int r = tid / 12, lane = tid - r*12;
    float s1 = 0.f, s2 = 0.f;
    for (int j = lane; j < DI; j += 12){
      float v = gs[r*WS + j];
      s1 += v; s2 += v*v;
    }
    ps[0][r][lane] = s1; ps[1][r][lane] = s2;
  }
  __syncthreads();
  if (tid < OT){
    float a = 0.f, bb = 0.f;
    #pragma unroll
    for (int j=0;j<12;j++){ a += ps[0][tid][j]; bb += ps[1][tid][j]; }
    float mu = a * (1.f/192.f);
    float var = bb * (1.f/192.f) - mu*mu;
    mv[0][tid] = mu; mv[1][tid] = rsqrtf(var + 1e-5f);
  }
  __syncthreads();
  // phase C: normalize + gate
  float lg = ln_g[d], lb = ln_b[d];
  #pragma unroll 4
  for (int r=0;r<OT;r++){
    float yn = (gs[r*WS + d] - mv[0][r]) * mv[1][r] * lg + lb;
    float zv = z[(size_t)(l0+r)*DI + d];
    gs[r*WS + d] = yn * (zv / (1.f + __expf(-zv)));
  }
  __syncthreads();
  // phase D: out_proj
  int half = tid / 96;             // rows half*8..half*8+7
  int e = tid - half*96;
  int r0 = half*8;
  float acc[8];
  #pragma unroll
  for (int i=0;i<8;i++) acc[i] = 0.f;
  const float4* wrow = (const float4*)(opw + e*DI);
  #pragma unroll 4
  for (int jc = 0; jc < DI/4; jc++){
    float4 w = wrow[jc];
    #pragma unroll
    for (int i=0;i<8;i++){
      float4 gv = *(const float4*)&gs[(r0+i)*WS + jc*4];
      acc[i] = fmaf(w.x,gv.x,fmaf(w.y,gv.y,fmaf(w.z,gv.z,fmaf(w.w,gv.w,acc[i]))));
    }
  }
  int f = sflag;
  #pragma unroll
  for (int i=0;i<8;i++){
    int l = l0 + r0 + i;
    if (f) ((__hip_bfloat16*)out)[l*DM + e] = __float2bfloat16(acc[i]);
    else   ((float*)out)[l*DM + e] = acc[i];
  }
}

extern "C" void kernel_launch(void* const* d_in, const int* in_sizes, int n_in,
                              void* d_out, int out_size, void* d_ws, size_t ws_size,
                              hipStream_t stream) {
  float* ws = (float*)d_ws;
  float* cvt = ws + 16;
  const int off[12] = {0,36864,38592,38784,67968,72576,73344,85632,86400,86592,86784,105216};
  float* c[12];
  c[0] = nullptr;                            // x stays raw
  for (int i = 1; i < 12; i++) c[i] = cvt + off[i-1];

  float* big    = cvt + 105216;
  float* xx     = big;                       // 786432
  float* z      = xx + (size_t)LL*DI;        // 786432
  float* xc     = z  + (size_t)LL*DI;        // 786432
  float* xct    = xc + (size_t)LL*DI;        // 786432
  float* dts    = xct + (size_t)LL*DI;       // 131072 (RKP=8 padded)
  float* Bb     = dts + (size_t)KD*LL*RKP;   // 262144
  float* Cb     = Bb + (size_t)KD*LL*NS;     // 262144
  float* PH     = Cb + (size_t)KD*LL*NS;     // 2*CHn*NC
  // footprint(CHB=7): ~53 MB; (CHB=6): ~47 MB. ws_size measured 256 MiB.
  size_t need128 = (size_t)(16 + 105216 + 4*786432 + 131072 + 2*262144
                            + 2*128*NC + 2*(size_t)KD*LL*DI) * 4;
  int chBits = (ws_size >= need128) ? 7 : 6;
  int CHn = 1 << chBits;
  float* SDb  = PH + 2*(size_t)CHn*NC;       // KD*LL*DI = 3145728
  float* ydir = SDb + (size_t)KD*LL*DI;      // KD*LL*DI = 3145728

  P12 ptrs;
  for (int i = 0; i < 12; i++) ptrs.p[i] = d_in[i];
  k_convert_all<<<(105216 + 255)/256, 256, 0, stream>>>(ptrs, cvt);

  k_inproj<<<LL/8, 384, 0, stream>>>(d_in[0], c[1], xx, z);
  k_conv<<<LL, DI, 0, stream>>>(xx, c[2], c[3], xc, xct);
  k_proj<<<KD*(LL/PT), 256, 0, stream>>>(xc, c[4], dts, Bb, Cb);
  if (chBits == 7){
    k_scan1<7><<<KD*3*128, 256, 0, stream>>>(xc, xct, dts, Bb, Cb, c[7], c[5], c[6],
                                             PH, SDb, ydir);
    k_scan2<7><<<NC/256, 256, 0, stream>>>((float2*)PH);
    k_corr<7><<<KD*128, 192, 0, stream>>>(Cb, c[7], (const float2*)PH, SDb, ydir);
  } else {
    k_scan1<6><<<KD*3*64, 256, 0, stream>>>(xc, xct, dts, Bb, Cb, c[7], c[5], c[6],
                                            PH, SDb, ydir);
    k_scan2<6><<<NC/256, 256, 0, stream>>>((float2*)PH);
    k_corr<6><<<KD*64, 192, 0, stream>>>(Cb, c[7], (const float2*)PH, SDb, ydir);
  }
  k_out<<<LL/OT, 192, 0, stream>>>(ydir, xc, z, c[8], c[9], c[10], c[11], d_out,
                                   (const unsigned short*)d_in[0]);
}